// Round 1
// baseline (1804.945 us; speedup 1.0000x reference)
//
#include <hip/hip_runtime.h>

#define T_ 512
#define B_ 128
#define I_ 512
#define H_ 512
#define O_ 12
#define NSTEP 16

typedef __attribute__((ext_vector_type(8))) short s16x8;
typedef __attribute__((ext_vector_type(4))) float f32x4;

__device__ __forceinline__ float bf2f(unsigned short u){
  union { unsigned int i; float f; } v; v.i = ((unsigned int)u) << 16; return v.f;
}
__device__ __forceinline__ unsigned short f2bf(float f){
  union { float f; unsigned int i; } v; v.f = f;
  unsigned int r = v.i + 0x7fffu + ((v.i >> 16) & 1u);
  return (unsigned short)(r >> 16);
}
__device__ __forceinline__ float fast_rcp(float x){ return __builtin_amdgcn_rcpf(x); }
__device__ __forceinline__ float fast_tanh(float x){
  float e = __expf(2.0f * x);
  return 1.0f - 2.0f * fast_rcp(e + 1.0f);
}
__device__ __forceinline__ float fast_sigmoid(float x){
  return fast_rcp(1.0f + __expf(-x));
}
__device__ __forceinline__ void gload16(const void* g, void* l){
  __builtin_amdgcn_global_load_lds((const __attribute__((address_space(1))) void*)g,
                                   (__attribute__((address_space(3))) void*)l, 16, 0, 0);
}

// ---------------- setup kernels ----------------

// x (f32) -> xb (bf16), 8 elems/thread
__global__ __launch_bounds__(256) void castx_k(const float* __restrict__ x,
                                               unsigned short* __restrict__ xb){
  int idx = blockIdx.x * 256 + threadIdx.x;      // 0 .. 4194303
  const float4* p = (const float4*)x + (size_t)idx * 2;
  float4 a = p[0], b = p[1];
  unsigned short tmp[8] = {f2bf(a.x), f2bf(a.y), f2bf(a.z), f2bf(a.w),
                           f2bf(b.x), f2bf(b.y), f2bf(b.z), f2bf(b.w)};
  *(s16x8*)(xb + (size_t)idx * 8) = *(const s16x8*)tmp;
}

// 512x512 f32 -> transposed bf16: dst[c*512+r] = src[r*512+c]
__global__ __launch_bounds__(256) void tcb_k(const float* __restrict__ src,
                                             unsigned short* __restrict__ dst){
  int idx = blockIdx.x * 256 + threadIdx.x;      // 0 .. 262143
  int r = idx >> 9, c = idx & 511;
  dst[(size_t)c * 512 + r] = f2bf(src[(size_t)r * 512 + c]);
}

// gate weight (12x512 f32) -> dst[h*12+o] (f32)
__global__ __launch_bounds__(256) void tfw_k(const float* __restrict__ src,
                                             float* __restrict__ dst){
  int idx = blockIdx.x * 256 + threadIdx.x;      // 0 .. 6143
  int o = idx >> 9, h = idx & 511;
  dst[h * 12 + o] = src[o * 512 + h];
}

// fc_w (512x12 f32) -> fcwT[o*512+h]
__global__ __launch_bounds__(256) void tfc_k(const float* __restrict__ src,
                                             float* __restrict__ dst){
  int idx = blockIdx.x * 256 + threadIdx.x;      // 0 .. 6143
  int h = idx / 12, o = idx - h * 12;
  dst[o * 512 + h] = src[h * 12 + o];
}

// ---------------- MFMA GEMM template ----------------
// A: MxK row-major bf16 (K=512), Bt: NxK row-major bf16 (i.e. B transposed).
// 128x128 block tile, BK=64, 4 waves of 64x64, 16x16x32 MFMA.
// LDS XOR-swizzle (16B-chunk ^ (row&7)) applied via pre-swizzled global source
// (linear global_load_lds dest) + swizzled ds_read address.
// EPI: 0=store bf16 (U)   1=tanh -> f32 + bf16 (s0)
//      2=store f32 (pre1) 3=gates r/z/c0 (see below) 4=sh + state update
template<int EPI>
__global__ __launch_bounds__(256) void gemm_k(
    const unsigned short* __restrict__ A, const unsigned short* __restrict__ Bt, int K,
    unsigned short* __restrict__ ob0, float* __restrict__ o0, float* __restrict__ o1,
    const float* __restrict__ e0, const float* __restrict__ e1,
    const float* __restrict__ e2, const float* __restrict__ e3){
  __shared__ unsigned short ldsA[128 * 64];
  __shared__ unsigned short ldsB[128 * 64];
  const int tid = threadIdx.x;
  const int lane = tid & 63, wid = tid >> 6;
  const int wr = wid >> 1, wc = wid & 1;
  const int m0 = blockIdx.y * 128, n0 = blockIdx.x * 128;
  f32x4 acc[4][4];
#pragma unroll
  for (int m = 0; m < 4; ++m)
#pragma unroll
    for (int n = 0; n < 4; ++n) acc[m][n] = (f32x4)0.0f;

  for (int kt = 0; kt < K; kt += 64){
    __syncthreads();
#pragma unroll
    for (int p = 0; p < 4; ++p){
      int s = p * 256 + tid;
      int row = s >> 3;
      int kc = (s & 7) ^ (row & 7);             // inverse-swizzled source chunk
      gload16(A  + (size_t)(m0 + row) * K + kt + kc * 8, &ldsA[s * 8]);
      gload16(Bt + (size_t)(n0 + row) * K + kt + kc * 8, &ldsB[s * 8]);
    }
    __syncthreads();
#pragma unroll
    for (int ks = 0; ks < 2; ++ks){
      int kc_l = (lane >> 4) + ks * 4;          // 16B chunk index within row
      s16x8 av[4], bv[4];
#pragma unroll
      for (int m = 0; m < 4; ++m){
        int r = wr * 64 + m * 16 + (lane & 15);
        av[m] = *(const s16x8*)&ldsA[r * 64 + ((kc_l ^ (r & 7)) << 3)];
      }
#pragma unroll
      for (int n = 0; n < 4; ++n){
        int c = wc * 64 + n * 16 + (lane & 15);
        bv[n] = *(const s16x8*)&ldsB[c * 64 + ((kc_l ^ (c & 7)) << 3)];
      }
#pragma unroll
      for (int m = 0; m < 4; ++m)
#pragma unroll
        for (int n = 0; n < 4; ++n)
          acc[m][n] = __builtin_amdgcn_mfma_f32_16x16x32_bf16(av[m], bv[n], acc[m][n], 0, 0, 0);
    }
  }

#pragma unroll
  for (int m = 0; m < 4; ++m){
#pragma unroll
    for (int n = 0; n < 4; ++n){
      int row_b = m0 + wr * 64 + m * 16 + ((lane >> 4) << 2);
      int col   = n0 + wc * 64 + n * 16 + (lane & 15);
#pragma unroll
      for (int q = 0; q < 4; ++q){
        float v = acc[m][n][q];
        int r_ = row_b + q;
        if constexpr (EPI == 0){
          ob0[(size_t)r_ * 512 + col] = f2bf(v);
        } else if constexpr (EPI == 1){
          float t = fast_tanh(v);
          o0[(size_t)r_ * 512 + col] = t;
          ob0[(size_t)r_ * 512 + col] = f2bf(t);
        } else if constexpr (EPI == 2){
          o0[(size_t)r_ * 1536 + col] = v;
        } else if constexpr (EPI == 3){
          // acc = c@[cr|cz|c0]; add out@W (e1=Wo2 packed [1536][12], e0=out[b][12])
          float op = 0.f;
          const float* wo = e1 + col * 12;
          const float* ob = e0 + r_ * 12;
#pragma unroll
          for (int o = 0; o < 12; ++o) op += ob[o] * wo[o];
          float v2 = v + op;
          if (col < 1024) v2 += e3[(size_t)r_ * 1536 + 512 + col];   // + s@{ur,uz}
          if (col < 512){                       // r-gate -> rs = r*s (bf16)
            float rg = fast_sigmoid(v2);
            ob0[(size_t)r_ * 512 + col] = f2bf(rg * e2[(size_t)r_ * 512 + col]);
          } else if (col < 1024){               // z-gate (f32)
            o0[(size_t)r_ * 512 + (col - 512)] = fast_sigmoid(v2);
          } else {                              // c@c0 + out@w0 (f32, pre-tanh part)
            o1[(size_t)r_ * 512 + (col - 1024)] = v2;
          }
        } else if constexpr (EPI == 4){
          // acc = (r*s)@u0; e0=cu0 (c@c0+out@w0), e1=z, o0=s_f32 (rw), ob0=s_bf
          float v2 = v + e0[(size_t)r_ * 512 + col];
          float sh = fast_tanh(v2);
          float z  = e1[(size_t)r_ * 512 + col];
          float so = o0[(size_t)r_ * 512 + col];
          float sn = (1.0f - z) * so + z * sh;
          o0[(size_t)r_ * 512 + col] = sn;
          ob0[(size_t)r_ * 512 + col] = f2bf(sn);
        }
      }
    }
  }
}

// ---------------- per-step kernels ----------------

// e[t,b] = sum_h tanh(sb[b,h] + U[tb,h]) * va[h]; one wave per (t,b) row.
__global__ __launch_bounds__(256) void e_k(const unsigned short* __restrict__ U,
    const float* __restrict__ pre1, const float* __restrict__ va,
    float* __restrict__ e_bt){
  int w = blockIdx.x * 4 + (threadIdx.x >> 6);   // tb row, 0..65535
  int lane = threadIdx.x & 63;
  int b = w & (B_ - 1);
  int t = w >> 7;
  s16x8 uv = *(const s16x8*)(U + (size_t)w * H_ + lane * 8);
  const float* sb = pre1 + (size_t)b * 1536 + lane * 8;
  float4 s0 = *(const float4*)sb, s1 = *(const float4*)(sb + 4);
  const float* vap = va + lane * 8;
  float4 v0 = *(const float4*)vap, v1 = *(const float4*)(vap + 4);
  float sum =
      fast_tanh(bf2f((unsigned short)uv[0]) + s0.x) * v0.x +
      fast_tanh(bf2f((unsigned short)uv[1]) + s0.y) * v0.y +
      fast_tanh(bf2f((unsigned short)uv[2]) + s0.z) * v0.z +
      fast_tanh(bf2f((unsigned short)uv[3]) + s0.w) * v0.w +
      fast_tanh(bf2f((unsigned short)uv[4]) + s1.x) * v1.x +
      fast_tanh(bf2f((unsigned short)uv[5]) + s1.y) * v1.y +
      fast_tanh(bf2f((unsigned short)uv[6]) + s1.z) * v1.z +
      fast_tanh(bf2f((unsigned short)uv[7]) + s1.w) * v1.w;
#pragma unroll
  for (int off = 32; off; off >>= 1) sum += __shfl_xor(sum, off, 64);
  if (lane == 0) e_bt[(size_t)b * T_ + t] = sum;
}

// per-b softmax normalizers: m[b], 1/den[b]; one wave per b.
__global__ __launch_bounds__(256) void red_k(const float* __restrict__ e_bt,
                                             float* __restrict__ mden){
  int b = blockIdx.x * 4 + (threadIdx.x >> 6);
  int lane = threadIdx.x & 63;
  const float* er = e_bt + (size_t)b * T_ + lane * 8;
  float4 a0 = *(const float4*)er, a1 = *(const float4*)(er + 4);
  float m = fmaxf(fmaxf(fmaxf(a0.x, a0.y), fmaxf(a0.z, a0.w)),
                  fmaxf(fmaxf(a1.x, a1.y), fmaxf(a1.z, a1.w)));
#pragma unroll
  for (int off = 32; off; off >>= 1) m = fmaxf(m, __shfl_xor(m, off, 64));
  float s = __expf(a0.x - m) + __expf(a0.y - m) + __expf(a0.z - m) + __expf(a0.w - m) +
            __expf(a1.x - m) + __expf(a1.y - m) + __expf(a1.z - m) + __expf(a1.w - m);
#pragma unroll
  for (int off = 32; off; off >>= 1) s += __shfl_xor(s, off, 64);
  if (lane == 0){ mden[b * 2] = m; mden[b * 2 + 1] = 1.0f / s; }
}

// partial c: block = 1 wave, handles (b, 32 t's); c_part[tc][b][i]
__global__ __launch_bounds__(64) void c_k(const unsigned short* __restrict__ xb,
    const float* __restrict__ e_bt, const float* __restrict__ mden,
    float* __restrict__ c_part){
  int tc = blockIdx.x, b = blockIdx.y;
  int lane = threadIdx.x;
  float m = mden[b * 2], rden = mden[b * 2 + 1];
  const float* eb = e_bt + (size_t)b * T_;
  float acc[8] = {0, 0, 0, 0, 0, 0, 0, 0};
  for (int j = 0; j < 32; ++j){
    int t = tc * 32 + j;
    float a = __expf(eb[t] - m) * rden;
    s16x8 xv = *(const s16x8*)(xb + ((size_t)t * B_ + b) * I_ + lane * 8);
#pragma unroll
    for (int k = 0; k < 8; ++k) acc[k] += a * bf2f((unsigned short)xv[k]);
  }
  float* cp = c_part + ((size_t)tc * B_ + b) * I_ + lane * 8;
#pragma unroll
  for (int k = 0; k < 8; ++k) cp[k] = acc[k];
}

// reduce 16 partials -> c (bf16)
__global__ __launch_bounds__(256) void creduce_k(const float* __restrict__ c_part,
                                                 unsigned short* __restrict__ cbf){
  int idx = blockIdx.x * 256 + threadIdx.x;      // 0..65535
  float s = 0.f;
#pragma unroll
  for (int tc = 0; tc < 16; ++tc) s += c_part[(size_t)tc * (B_ * I_) + idx];
  cbf[idx] = f2bf(s);
}

// out[b,o] = s@fc_w + fc_b; write outb + d_out slice. One wave per (b,o).
__global__ __launch_bounds__(256) void out_k(const float* __restrict__ s_f32,
    const float* __restrict__ fcwT, const float* __restrict__ fcb,
    float* __restrict__ outb, float* __restrict__ dout, int step){
  int w = blockIdx.x * 4 + (threadIdx.x >> 6);   // 0..1535
  int lane = threadIdx.x & 63;
  int b = w / 12, o = w - b * 12;
  const float* sp = s_f32 + (size_t)b * H_ + lane * 8;
  const float* fp = fcwT + (size_t)o * H_ + lane * 8;
  float4 sa = *(const float4*)sp, sb = *(const float4*)(sp + 4);
  float4 fa = *(const float4*)fp, fb = *(const float4*)(fp + 4);
  float sum = sa.x * fa.x + sa.y * fa.y + sa.z * fa.z + sa.w * fa.w +
              sb.x * fb.x + sb.y * fb.y + sb.z * fb.z + sb.w * fb.w;
#pragma unroll
  for (int off = 32; off; off >>= 1) sum += __shfl_xor(sum, off, 64);
  if (lane == 0){
    float v = sum + fcb[o];
    outb[b * 12 + o] = v;
    dout[(size_t)b * (NSTEP * O_) + step * O_ + o] = v;
  }
}

// ---------------- host launch ----------------
extern "C" void kernel_launch(void* const* d_in, const int* in_sizes, int n_in,
                              void* d_out, int out_size, void* d_ws, size_t ws_size,
                              hipStream_t stream){
  const float* x   = (const float*)d_in[0];
  const float* w0  = (const float*)d_in[1];
  const float* wz  = (const float*)d_in[2];
  const float* wrm = (const float*)d_in[3];
  const float* wsm = (const float*)d_in[4];
  const float* wa  = (const float*)d_in[5];
  const float* ua  = (const float*)d_in[6];
  const float* va  = (const float*)d_in[7];
  const float* u0  = (const float*)d_in[8];
  const float* uz  = (const float*)d_in[9];
  const float* urm = (const float*)d_in[10];
  const float* c0  = (const float*)d_in[11];
  const float* cz  = (const float*)d_in[12];
  const float* cr  = (const float*)d_in[13];
  const float* fcw = (const float*)d_in[14];
  const float* fcb = (const float*)d_in[15];
  float* dout = (float*)d_out;

  char* base = (char*)d_ws;
  size_t off = 0;
  auto alloc = [&](size_t bytes) -> char* {
    char* p = base + off; off += (bytes + 255) & ~(size_t)255; return p;
  };
  unsigned short* xb   = (unsigned short*)alloc((size_t)T_ * B_ * I_ * 2);
  unsigned short* U    = (unsigned short*)alloc((size_t)T_ * B_ * H_ * 2);
  unsigned short* Pua  = (unsigned short*)alloc(512 * 512 * 2);
  unsigned short* Pws  = (unsigned short*)alloc(512 * 512 * 2);
  unsigned short* P1   = (unsigned short*)alloc(1536 * 512 * 2);
  unsigned short* P2   = (unsigned short*)alloc(1536 * 512 * 2);
  unsigned short* P3   = (unsigned short*)alloc(512 * 512 * 2);
  float* Wo2           = (float*)alloc(1536 * 12 * 4);
  float* fcwT          = (float*)alloc(12 * 512 * 4);
  float* pre1          = (float*)alloc((size_t)B_ * 1536 * 4);
  float* e_bt          = (float*)alloc((size_t)B_ * T_ * 4);
  float* mden          = (float*)alloc(B_ * 2 * 4);
  float* c_part        = (float*)alloc((size_t)16 * B_ * I_ * 4);
  unsigned short* cbf  = (unsigned short*)alloc((size_t)B_ * I_ * 2);
  unsigned short* rsb  = (unsigned short*)alloc((size_t)B_ * H_ * 2);
  float* zbuf          = (float*)alloc((size_t)B_ * H_ * 4);
  float* cu0           = (float*)alloc((size_t)B_ * H_ * 4);
  float* s_f32         = (float*)alloc((size_t)B_ * H_ * 4);
  unsigned short* s_bf = (unsigned short*)alloc((size_t)B_ * H_ * 2);
  float* outb          = (float*)alloc(B_ * O_ * 4);
  (void)ws_size; (void)in_sizes; (void)n_in; (void)out_size;

  // ---- setup ----
  castx_k<<<16384, 256, 0, stream>>>(x, xb);
  tcb_k<<<1024, 256, 0, stream>>>(ua, Pua);
  tcb_k<<<1024, 256, 0, stream>>>(wsm, Pws);
  tcb_k<<<1024, 256, 0, stream>>>(wa, P1);
  tcb_k<<<1024, 256, 0, stream>>>(urm, P1 + 512 * 512);
  tcb_k<<<1024, 256, 0, stream>>>(uz, P1 + 1024 * 512);
  tcb_k<<<1024, 256, 0, stream>>>(cr, P2);
  tcb_k<<<1024, 256, 0, stream>>>(cz, P2 + 512 * 512);
  tcb_k<<<1024, 256, 0, stream>>>(c0, P2 + 1024 * 512);
  tcb_k<<<1024, 256, 0, stream>>>(u0, P3);
  tfw_k<<<24, 256, 0, stream>>>(wrm, Wo2);
  tfw_k<<<24, 256, 0, stream>>>(wz, Wo2 + 512 * 12);
  tfw_k<<<24, 256, 0, stream>>>(w0, Wo2 + 1024 * 12);
  tfc_k<<<24, 256, 0, stream>>>(fcw, fcwT);

  // U = x @ ua  (bf16 out)
  gemm_k<0><<<dim3(4, 512), 256, 0, stream>>>(xb, Pua, 512, U, nullptr, nullptr,
                                              nullptr, nullptr, nullptr, nullptr);
  // s0 = tanh(x[0] @ ws)
  gemm_k<1><<<dim3(4, 1), 256, 0, stream>>>(xb, Pws, 512, s_bf, s_f32, nullptr,
                                            nullptr, nullptr, nullptr, nullptr);
  out_k<<<384, 256, 0, stream>>>(s_f32, fcwT, fcb, outb, dout, 0);

  // ---- recurrence ----
  for (int step = 1; step < NSTEP; ++step){
    // pre1 = s @ [wa | ur | uz]
    gemm_k<2><<<dim3(12, 1), 256, 0, stream>>>(s_bf, P1, 512, nullptr, pre1, nullptr,
                                               nullptr, nullptr, nullptr, nullptr);
    e_k<<<16384, 256, 0, stream>>>(U, pre1, va, e_bt);
    red_k<<<32, 256, 0, stream>>>(e_bt, mden);
    c_k<<<dim3(16, B_), 64, 0, stream>>>(xb, e_bt, mden, c_part);
    creduce_k<<<256, 256, 0, stream>>>(c_part, cbf);
    // c @ [cr|cz|c0] + out@W + s@{ur,uz} -> rs (bf16), z, cu0
    gemm_k<3><<<dim3(12, 1), 256, 0, stream>>>(cbf, P2, 512, rsb, zbuf, cu0,
                                               outb, Wo2, s_f32, pre1);
    // (r*s) @ u0 -> sh -> s update
    gemm_k<4><<<dim3(4, 1), 256, 0, stream>>>(rsb, P3, 512, s_bf, s_f32, nullptr,
                                              cu0, zbuf, nullptr, nullptr);
    out_k<<<384, 256, 0, stream>>>(s_f32, fcwT, fcb, outb, dout, step);
  }
}